// Round 8
// baseline (430.255 us; speedup 1.0000x reference)
//
#include <hip/hip_runtime.h>

// Emformer convolution module, MI355X/gfx950.
// Pipeline: cast weights -> LN1 -> GEMM1+GLU (bf16 MFMA) -> dwconv+LN2+SiLU -> GEMM2+residual -> state.
// R1-R6 history: conv streaming 16-row tiles (fits 64-VGPR budget of 512-thr blocks), cwT coalesced,
//   gemm XCD-friendly decode bm=bid%640. R7 profile: gemm1 125us, latency-bound (1-phase loop,
//   vmcnt drained before compute every iteration).
// R7: GEMMs -> minimal 2-phase double-buffered pipeline (T3 recipe): BK=32, prefetch next tile
//   before compute, ONE barrier per iteration. LDS: gemm1 48KB, gemm2 32KB.

#define Dm 512
#define STATE 30
#define Uu 2048
#define Rr 512
#define Bb 32
#define Tt 2560        // Rr + Uu
#define MROWS 81920    // Tt * Bb

typedef unsigned short u16;
typedef unsigned int u32;
typedef __attribute__((ext_vector_type(8))) __bf16 bf16x8;
typedef __attribute__((ext_vector_type(4))) float f32x4;

__device__ __forceinline__ u16 f2bf(float x) {
  u32 u = __float_as_uint(x);
  u += 0x7fff + ((u >> 16) & 1);   // RNE
  return (u16)(u >> 16);
}
__device__ __forceinline__ float bf2f(u16 h) {
  return __uint_as_float((u32)h << 16);
}
__device__ __forceinline__ void load_lds16(const void* g, void* l) {
  __builtin_amdgcn_global_load_lds(
      (const __attribute__((address_space(1))) void*)g,
      (__attribute__((address_space(3))) void*)l, 16, 0, 0);
}

// ---------------- cast f32 -> bf16 (weights) ----------------
__global__ __launch_bounds__(256, 4) void k_cast(const float* __restrict__ src,
                                                 u16* __restrict__ dst, int n) {
  int i = (blockIdx.x * 256 + threadIdx.x) * 4;
  if (i >= n) return;
  float4 v = *(const float4*)(src + i);
  u32 lo = (u32)f2bf(v.x) | ((u32)f2bf(v.y) << 16);
  u32 hi = (u32)f2bf(v.z) | ((u32)f2bf(v.w) << 16);
  *(uint2*)(dst + i) = make_uint2(lo, hi);
}

// ---------------- transpose conv weight: cw[512][31] -> cwT[31][512] ----------------
__global__ __launch_bounds__(256, 4) void k_wt(const float* __restrict__ cw,
                                               float* __restrict__ cwT) {
  int i = blockIdx.x * 256 + threadIdx.x;
  if (i >= 31 * 512) return;
  int k = i >> 9, d = i & 511;
  cwT[i] = cw[d * 31 + k];
}

// ---------------- LN1: concat(rc, utt) -> bf16 ----------------
__global__ __launch_bounds__(256, 4) void k_ln1(const float* __restrict__ utt,
                                                const float* __restrict__ rc,
                                                const float* __restrict__ g,
                                                const float* __restrict__ b,
                                                u16* __restrict__ out) {
  int wid = threadIdx.x >> 6, lane = threadIdx.x & 63;
  long row = (long)blockIdx.x * 4 + wid;  // token index tau = t*B + b
  const float* src = (row < (long)Rr * Bb) ? rc + row * Dm
                                           : utt + (row - (long)Rr * Bb) * Dm;
  int d0 = lane * 8;
  float4 v0 = *(const float4*)(src + d0);
  float4 v1 = *(const float4*)(src + d0 + 4);
  float s = v0.x + v0.y + v0.z + v0.w + v1.x + v1.y + v1.z + v1.w;
  float ss = v0.x * v0.x + v0.y * v0.y + v0.z * v0.z + v0.w * v0.w +
             v1.x * v1.x + v1.y * v1.y + v1.z * v1.z + v1.w * v1.w;
#pragma unroll
  for (int off = 1; off < 64; off <<= 1) {
    s += __shfl_xor(s, off);
    ss += __shfl_xor(ss, off);
  }
  float mean = s * (1.f / 512.f);
  float var = ss * (1.f / 512.f) - mean * mean;
  float rstd = rsqrtf(var + 1e-5f);
  float4 g0 = *(const float4*)(g + d0);
  float4 g1 = *(const float4*)(g + d0 + 4);
  float4 b0 = *(const float4*)(b + d0);
  float4 b1v = *(const float4*)(b + d0 + 4);
  float o[8];
  o[0] = (v0.x - mean) * rstd * g0.x + b0.x;
  o[1] = (v0.y - mean) * rstd * g0.y + b0.y;
  o[2] = (v0.z - mean) * rstd * g0.z + b0.z;
  o[3] = (v0.w - mean) * rstd * g0.w + b0.w;
  o[4] = (v1.x - mean) * rstd * g1.x + b1v.x;
  o[5] = (v1.y - mean) * rstd * g1.y + b1v.y;
  o[6] = (v1.z - mean) * rstd * g1.z + b1v.z;
  o[7] = (v1.w - mean) * rstd * g1.w + b1v.w;
  u32 p[4];
#pragma unroll
  for (int i = 0; i < 4; ++i)
    p[i] = (u32)f2bf(o[2 * i]) | ((u32)f2bf(o[2 * i + 1]) << 16);
  *(uint4*)(out + row * Dm + d0) = make_uint4(p[0], p[1], p[2], p[3]);
}

// ---------------- GEMM1 + GLU (2-phase dbuf, BK=32) ----------------
__global__ __launch_bounds__(256, 2) void k_gemm1(const u16* __restrict__ A,
                                                  const u16* __restrict__ Wb,
                                                  const float* __restrict__ b1,
                                                  u16* __restrict__ X) {
  __shared__ __align__(16) u16 sA[2][128 * 32], sBa[2][128 * 32], sBg[2][128 * 32];
  int tid = threadIdx.x;
  int bid = blockIdx.x;
  int bm = bid % 640, nt = bid / 640;  // A-panel sharers -> same XCD (640 % 8 == 0)
  long arow0 = (long)bm * 128;
  int ncol0 = nt * 128;
  int lane = tid & 63, wid = tid >> 6;
  int wm = (wid >> 1) * 64, wn = (wid & 1) * 64;
  int lr = lane & 15, kg = lane >> 4;

  f32x4 acc_a[4][4], acc_g[4][4];
#pragma unroll
  for (int i = 0; i < 4; ++i)
#pragma unroll
    for (int j = 0; j < 4; ++j) {
      acc_a[i][j] = (f32x4)0.f;
      acc_g[i][j] = (f32x4)0.f;
    }

  // staging: 128x32 tile = 512 chunks of 8 elems; 2 chunks/thread
  auto STAGE = [&](int buf, int k0) {
#pragma unroll
    for (int i = 0; i < 2; ++i) {
      int c = i * 256 + tid;
      int r = c >> 2, col = (c & 3) * 8;
      load_lds16(A + (arow0 + r) * 512 + k0 + col, &sA[buf][c * 8]);
      load_lds16(Wb + (long)(ncol0 + r) * 512 + k0 + col, &sBa[buf][c * 8]);
      load_lds16(Wb + (long)(512 + ncol0 + r) * 512 + k0 + col, &sBg[buf][c * 8]);
    }
  };

  STAGE(0, 0);
  __syncthreads();
  for (int it = 0; it < 16; ++it) {
    int cur = it & 1;
    if (it < 15) STAGE(cur ^ 1, (it + 1) * 32);  // prefetch next tile (in flight across compute)
    bf16x8 av[4], bav[4], bgv[4];
#pragma unroll
    for (int i = 0; i < 4; ++i) {
      av[i] = *(const bf16x8*)&sA[cur][(wm + i * 16 + lr) * 32 + kg * 8];
      bav[i] = *(const bf16x8*)&sBa[cur][(wn + i * 16 + lr) * 32 + kg * 8];
      bgv[i] = *(const bf16x8*)&sBg[cur][(wn + i * 16 + lr) * 32 + kg * 8];
    }
#pragma unroll
    for (int mi = 0; mi < 4; ++mi)
#pragma unroll
      for (int ni = 0; ni < 4; ++ni) {
        acc_a[mi][ni] = __builtin_amdgcn_mfma_f32_16x16x32_bf16(
            av[mi], bav[ni], acc_a[mi][ni], 0, 0, 0);
        acc_g[mi][ni] = __builtin_amdgcn_mfma_f32_16x16x32_bf16(
            av[mi], bgv[ni], acc_g[mi][ni], 0, 0, 0);
      }
    __syncthreads();  // single barrier/iter: drains prefetch AFTER compute
  }
  int mg = kg * 4;
#pragma unroll
  for (int mi = 0; mi < 4; ++mi) {
#pragma unroll
    for (int ni = 0; ni < 4; ++ni) {
      int ncol = ncol0 + wn + ni * 16 + lr;
      float ba = b1[ncol], bg = b1[512 + ncol];
#pragma unroll
      for (int rgi = 0; rgi < 4; ++rgi) {
        long row = arow0 + wm + mi * 16 + mg + rgi;
        float a = acc_a[mi][ni][rgi] + ba;
        float gg = acc_g[mi][ni][rgi] + bg;
        float val = a / (1.f + __expf(-gg));
        X[row * 512 + ncol] = f2bf(val);
      }
    }
  }
}

// ---------------- depthwise conv + LN2 + SiLU ----------------
// grid (160, 32): tile<128 utt 16-step tiles (tiles 0..1 touch state);
// 128..143 rc h=0 (s=tile-128); 144..159 rc h=1 (s=tile-144).
// 512 threads, thread = channel d. Streaming: transient x, static FMA fan-out.
// Per-thread live set (31 w + 16 acc + transients) fits the 64-VGPR budget.
__global__ __launch_bounds__(512, 4) void k_conv_ln2(
    const u16* __restrict__ X, const float* __restrict__ state,
    const float* __restrict__ cwT, const float* __restrict__ cb,
    const float* __restrict__ g2, const float* __restrict__ bt2,
    u16* __restrict__ Z) {
  __shared__ float ys[16][512];
  __shared__ float stats[16][2];
  int d = threadIdx.x;
  int tile = blockIdx.x, b = blockIdx.y;

  float w[31];
#pragma unroll
  for (int k = 0; k < 31; ++k) w[k] = cwT[k * 512 + d];  // coalesced
  float cbd = cb[d];
  float acc[16];
#pragma unroll
  for (int r = 0; r < 16; ++r) acc[r] = cbd;

  const u16* Xc = X + (long)b * 512 + d;  // column base; row stride 16384 elems
  auto xrow = [&](long trow) -> float { return bf2f(Xc[trow * (long)(Bb * Dm)]); };
  auto step = [&](int j, float x) {
#pragma unroll
    for (int r = 0; r < 16; ++r) {
      int k = j - r;
      if (k >= 0 && k < 31) acc[r] += x * w[k];
    }
  };

  if (tile < 128) {
    long t0 = (long)tile * 16;
    if (tile < 2) {
      // window reaches before utterance start: per-element state-vs-X select
      const float* st = state + ((long)b * 512 + d) * 30;
#pragma unroll
      for (int j = 0; j < 46; ++j) {
        long tj = t0 - 30 + j;
        float x = (tj < 0) ? st[tj + 30] : xrow(Rr + tj);
        step(j, x);
        if ((j & 15) == 15) __builtin_amdgcn_sched_barrier(0);
      }
    } else {
      long r0 = (long)Rr + t0 - 30;
#pragma unroll
      for (int j = 0; j < 46; ++j) {
        step(j, xrow(r0 + j));
        if ((j & 15) == 15) __builtin_amdgcn_sched_barrier(0);
      }
    }
  } else if (tile < 144) {
    int s = tile - 128;
    long rp = (long)Rr + 128 * (s + 1) - 30;  // pads, j 0..29
    long rm = (long)32 * s - 30;              // body, j 30..45
#pragma unroll
    for (int j = 0; j < 30; ++j) {
      step(j, xrow(rp + j));
      if ((j & 15) == 15) __builtin_amdgcn_sched_barrier(0);
    }
#pragma unroll
    for (int j = 30; j < 46; ++j) step(j, xrow(rm + j));
  } else {
    int s = tile - 144;
    long rp = (long)Rr + 128 * (s + 1) - 14;  // pads, j 0..13
    long rm = (long)32 * s - 14;              // body, j 14..45
#pragma unroll
    for (int j = 0; j < 14; ++j) step(j, xrow(rp + j));
    __builtin_amdgcn_sched_barrier(0);
#pragma unroll
    for (int j = 14; j < 46; ++j) {
      step(j, xrow(rm + j));
      if ((j & 15) == 15) __builtin_amdgcn_sched_barrier(0);
    }
  }

#pragma unroll
  for (int r = 0; r < 16; ++r) ys[r][d] = acc[r];
  __syncthreads();

  int wid = d >> 6, lane = d & 63;
#pragma unroll
  for (int rr = 0; rr < 2; ++rr) {
    int r = wid * 2 + rr;
    float4 va = *(const float4*)&ys[r][lane * 8];
    float4 vb = *(const float4*)&ys[r][lane * 8 + 4];
    float s = va.x + va.y + va.z + va.w + vb.x + vb.y + vb.z + vb.w;
    float ss = va.x * va.x + va.y * va.y + va.z * va.z + va.w * va.w +
               vb.x * vb.x + vb.y * vb.y + vb.z * vb.z + vb.w * vb.w;
#pragma unroll
    for (int off = 1; off < 64; off <<= 1) {
      s += __shfl_xor(s, off);
      ss += __shfl_xor(ss, off);
    }
    if (lane == 0) {
      float mean = s * (1.f / 512.f);
      float var = ss * (1.f / 512.f) - mean * mean;
      stats[r][0] = mean;
      stats[r][1] = rsqrtf(var + 1e-5f);
    }
  }
  __syncthreads();

  float gg = g2[d], bb = bt2[d];
  long orow0;
  if (tile < 128) {
    orow0 = ((long)Rr + tile * 16) * Bb + b;
  } else if (tile < 144) {
    orow0 = (long)(32 * (tile - 128)) * Bb + b;
  } else {
    orow0 = (long)(32 * (tile - 144) + 16) * Bb + b;
  }
#pragma unroll
  for (int r = 0; r < 16; ++r) {
    float mean = stats[r][0], rstd = stats[r][1];
    float y = (acc[r] - mean) * rstd * gg + bb;
    float zz = y / (1.f + __expf(-y));
    Z[(orow0 + (long)r * Bb) * 512 + d] = f2bf(zz);
  }
}

// ---------------- GEMM2 + bias + residual (2-phase dbuf, BK=32) ----------------
__global__ __launch_bounds__(256, 2) void k_gemm2(const u16* __restrict__ A,
                                                  const u16* __restrict__ Wb,
                                                  const float* __restrict__ b2,
                                                  const float* __restrict__ utt,
                                                  const float* __restrict__ rc,
                                                  float* __restrict__ out) {
  __shared__ __align__(16) u16 sA[2][128 * 32], sB[2][128 * 32];
  int tid = threadIdx.x;
  int bid = blockIdx.x;
  int bm = bid % 640, nt = bid / 640;  // A-panel sharers -> same XCD
  long arow0 = (long)bm * 128;
  int ncol0 = nt * 128;
  int lane = tid & 63, wid = tid >> 6;
  int wm = (wid >> 1) * 64, wn = (wid & 1) * 64;
  int lr = lane & 15, kg = lane >> 4;

  f32x4 acc[4][4];
#pragma unroll
  for (int i = 0; i < 4; ++i)
#pragma unroll
    for (int j = 0; j < 4; ++j) acc[i][j] = (f32x4)0.f;

  auto STAGE = [&](int buf, int k0) {
#pragma unroll
    for (int i = 0; i < 2; ++i) {
      int c = i * 256 + tid;
      int r = c >> 2, col = (c & 3) * 8;
      load_lds16(A + (arow0 + r) * 512 + k0 + col, &sA[buf][c * 8]);
      load_lds16(Wb + (long)(ncol0 + r) * 512 + k0 + col, &sB[buf][c * 8]);
    }
  };

  STAGE(0, 0);
  __syncthreads();
  for (int it = 0; it < 16; ++it) {
    int cur = it & 1;
    if (it < 15) STAGE(cur ^ 1, (it + 1) * 32);
    bf16x8 av[4], bv[4];
#pragma unroll
    for (int i = 0; i < 4; ++i) {
      av[i] = *(const bf16x8*)&sA[cur][(wm + i * 16 + lr) * 32 + kg * 8];
      bv[i] = *(const bf16x8*)&sB[cur][(wn + i * 16 + lr) * 32 + kg * 8];
    }
#pragma unroll
    for (int mi = 0; mi < 4; ++mi)
#pragma unroll
      for (int ni = 0; ni < 4; ++ni)
        acc[mi][ni] = __builtin_amdgcn_mfma_f32_16x16x32_bf16(
            av[mi], bv[ni], acc[mi][ni], 0, 0, 0);
    __syncthreads();
  }
  int mg = kg * 4;
#pragma unroll
  for (int mi = 0; mi < 4; ++mi) {
#pragma unroll
    for (int ni = 0; ni < 4; ++ni) {
      int ncol = ncol0 + wn + ni * 16 + lr;
      float bv = b2[ncol];
#pragma unroll
      for (int rgi = 0; rgi < 4; ++rgi) {
        long row = arow0 + wm + mi * 16 + mg + rgi;  // tau
        float val = acc[mi][ni][rgi] + bv;
        const float* src = (row < 16384) ? rc + row * 512 : utt + (row - 16384) * 512;
        val += src[ncol];
        float* dst = (row < 16384) ? out + 33554432 + row * 512
                                   : out + (row - 16384) * 512;
        dst[ncol] = val;
      }
    }
  }
}

// ---------------- new_state ----------------
__global__ __launch_bounds__(256, 4) void k_state(const u16* __restrict__ X,
                                                  float* __restrict__ out) {
  int i = blockIdx.x * 256 + threadIdx.x;
  if (i >= 491520) return;
  int j = i % 30;
  int rest = i / 30;
  int d = rest & 511;
  int b = rest >> 9;
  out[41943040 + i] = bf2f(X[((long)(2530 + j) * Bb + b) * 512 + d]);
}

extern "C" void kernel_launch(void* const* d_in, const int* in_sizes, int n_in,
                              void* d_out, int out_size, void* d_ws, size_t ws_size,
                              hipStream_t stream) {
  const float* utt = (const float*)d_in[0];
  const float* rc = (const float*)d_in[1];
  const float* state = (const float*)d_in[2];
  const float* ln1g = (const float*)d_in[3];
  const float* ln1b = (const float*)d_in[4];
  const float* w1 = (const float*)d_in[5];
  const float* b1 = (const float*)d_in[6];
  const float* cw = (const float*)d_in[7];
  const float* cb = (const float*)d_in[8];
  const float* ln2g = (const float*)d_in[9];
  const float* ln2b = (const float*)d_in[10];
  const float* w2 = (const float*)d_in[11];
  const float* b2 = (const float*)d_in[12];
  float* out = (float*)d_out;

  char* ws = (char*)d_ws;
  u16* w1b = (u16*)ws;                                         // 1 MB
  u16* w2b = (u16*)(ws + (1 << 20));                           // 512 KB
  float* cwT = (float*)(ws + (1 << 20) + (1 << 19));           // 64 KB
  u16* lnx = (u16*)(ws + (1 << 20) + (1 << 19) + (1 << 16));   // 80 MiB (ln_x, later z)
  u16* xbuf = lnx + (size_t)MROWS * Dm;                        // 80 MiB

  k_cast<<<512, 256, 0, stream>>>(w1, w1b, 1024 * 512);
  k_cast<<<256, 256, 0, stream>>>(w2, w2b, 512 * 512);
  k_wt<<<62, 256, 0, stream>>>(cw, cwT);
  k_ln1<<<MROWS / 4, 256, 0, stream>>>(utt, rc, ln1g, ln1b, lnx);
  k_gemm1<<<2560, 256, 0, stream>>>(lnx, w1b, b1, xbuf);
  k_conv_ln2<<<dim3(160, 32), 512, 0, stream>>>(xbuf, state, cwT, cb, ln2g, ln2b, lnx);
  k_gemm2<<<2560, 256, 0, stream>>>(lnx, w2b, b2, utt, rc, out);
  k_state<<<1920, 256, 0, stream>>>(xbuf, out);
}

// Round 9
// 393.660 us; speedup vs baseline: 1.0930x; 1.0930x over previous
//
#include <hip/hip_runtime.h>

// Emformer convolution module, MI355X/gfx950.
// Pipeline: cast weights -> LN1 -> GEMM1+GLU (bf16 MFMA) -> dwconv+LN2+SiLU -> GEMM2+residual -> state.
// R1-R6: conv streaming 16-row tiles, cwT coalesced. R6 = 389us baseline.
// R7 LESSON: __syncthreads drains vmcnt(0) -> BK=32 "prefetch" gave only ~100cyc overlap but 2x the
//   barrier stalls; gemm2 95->146us. Also %640 decode = A-sharers in successive dispatch
//   generations -> L3 eviction -> gemm1 FETCH 2.1x ideal.
// R8: gemm1 = R6 1-phase BK=64 + decode bid>>2 (sharers concurrent -> A HBM-read once).
//     gemm2 = BK=64 dbuf, prefetch-before-compute, one barrier/iter (8 stalls, ~300cyc overlap each).

#define Dm 512
#define STATE 30
#define Uu 2048
#define Rr 512
#define Bb 32
#define Tt 2560        // Rr + Uu
#define MROWS 81920    // Tt * Bb

typedef unsigned short u16;
typedef unsigned int u32;
typedef __attribute__((ext_vector_type(8))) __bf16 bf16x8;
typedef __attribute__((ext_vector_type(4))) float f32x4;

__device__ __forceinline__ u16 f2bf(float x) {
  u32 u = __float_as_uint(x);
  u += 0x7fff + ((u >> 16) & 1);   // RNE
  return (u16)(u >> 16);
}
__device__ __forceinline__ float bf2f(u16 h) {
  return __uint_as_float((u32)h << 16);
}
__device__ __forceinline__ void load_lds16(const void* g, void* l) {
  __builtin_amdgcn_global_load_lds(
      (const __attribute__((address_space(1))) void*)g,
      (__attribute__((address_space(3))) void*)l, 16, 0, 0);
}

// ---------------- cast f32 -> bf16 (weights) ----------------
__global__ __launch_bounds__(256, 4) void k_cast(const float* __restrict__ src,
                                                 u16* __restrict__ dst, int n) {
  int i = (blockIdx.x * 256 + threadIdx.x) * 4;
  if (i >= n) return;
  float4 v = *(const float4*)(src + i);
  u32 lo = (u32)f2bf(v.x) | ((u32)f2bf(v.y) << 16);
  u32 hi = (u32)f2bf(v.z) | ((u32)f2bf(v.w) << 16);
  *(uint2*)(dst + i) = make_uint2(lo, hi);
}

// ---------------- transpose conv weight: cw[512][31] -> cwT[31][512] ----------------
__global__ __launch_bounds__(256, 4) void k_wt(const float* __restrict__ cw,
                                               float* __restrict__ cwT) {
  int i = blockIdx.x * 256 + threadIdx.x;
  if (i >= 31 * 512) return;
  int k = i >> 9, d = i & 511;
  cwT[i] = cw[d * 31 + k];
}

// ---------------- LN1: concat(rc, utt) -> bf16 ----------------
__global__ __launch_bounds__(256, 4) void k_ln1(const float* __restrict__ utt,
                                                const float* __restrict__ rc,
                                                const float* __restrict__ g,
                                                const float* __restrict__ b,
                                                u16* __restrict__ out) {
  int wid = threadIdx.x >> 6, lane = threadIdx.x & 63;
  long row = (long)blockIdx.x * 4 + wid;  // token index tau = t*B + b
  const float* src = (row < (long)Rr * Bb) ? rc + row * Dm
                                           : utt + (row - (long)Rr * Bb) * Dm;
  int d0 = lane * 8;
  float4 v0 = *(const float4*)(src + d0);
  float4 v1 = *(const float4*)(src + d0 + 4);
  float s = v0.x + v0.y + v0.z + v0.w + v1.x + v1.y + v1.z + v1.w;
  float ss = v0.x * v0.x + v0.y * v0.y + v0.z * v0.z + v0.w * v0.w +
             v1.x * v1.x + v1.y * v1.y + v1.z * v1.z + v1.w * v1.w;
#pragma unroll
  for (int off = 1; off < 64; off <<= 1) {
    s += __shfl_xor(s, off);
    ss += __shfl_xor(ss, off);
  }
  float mean = s * (1.f / 512.f);
  float var = ss * (1.f / 512.f) - mean * mean;
  float rstd = rsqrtf(var + 1e-5f);
  float4 g0 = *(const float4*)(g + d0);
  float4 g1 = *(const float4*)(g + d0 + 4);
  float4 b0 = *(const float4*)(b + d0);
  float4 b1v = *(const float4*)(b + d0 + 4);
  float o[8];
  o[0] = (v0.x - mean) * rstd * g0.x + b0.x;
  o[1] = (v0.y - mean) * rstd * g0.y + b0.y;
  o[2] = (v0.z - mean) * rstd * g0.z + b0.z;
  o[3] = (v0.w - mean) * rstd * g0.w + b0.w;
  o[4] = (v1.x - mean) * rstd * g1.x + b1v.x;
  o[5] = (v1.y - mean) * rstd * g1.y + b1v.y;
  o[6] = (v1.z - mean) * rstd * g1.z + b1v.z;
  o[7] = (v1.w - mean) * rstd * g1.w + b1v.w;
  u32 p[4];
#pragma unroll
  for (int i = 0; i < 4; ++i)
    p[i] = (u32)f2bf(o[2 * i]) | ((u32)f2bf(o[2 * i + 1]) << 16);
  *(uint4*)(out + row * Dm + d0) = make_uint4(p[0], p[1], p[2], p[3]);
}

// ---------------- GEMM1 + GLU (1-phase BK=64, R6-verified) ----------------
__global__ __launch_bounds__(256, 2) void k_gemm1(const u16* __restrict__ A,
                                                  const u16* __restrict__ Wb,
                                                  const float* __restrict__ b1,
                                                  u16* __restrict__ X) {
  __shared__ __align__(16) u16 sA[128 * 64], sBa[128 * 64], sBg[128 * 64];
  int tid = threadIdx.x;
  int bid = blockIdx.x;
  int bm = bid >> 2, nt = bid & 3;  // A-panel sharers adjacent -> concurrent -> L3 reuse
  long arow0 = (long)bm * 128;
  int ncol0 = nt * 128;
  int lane = tid & 63, wid = tid >> 6;
  int wm = (wid >> 1) * 64, wn = (wid & 1) * 64;
  int lr = lane & 15, kg = lane >> 4;

  f32x4 acc_a[4][4], acc_g[4][4];
#pragma unroll
  for (int i = 0; i < 4; ++i)
#pragma unroll
    for (int j = 0; j < 4; ++j) {
      acc_a[i][j] = (f32x4)0.f;
      acc_g[i][j] = (f32x4)0.f;
    }

  for (int k0 = 0; k0 < 512; k0 += 64) {
#pragma unroll
    for (int i = 0; i < 4; ++i) {
      int c = i * 256 + tid;
      int r = c >> 3, col = (c & 7) * 8;
      load_lds16(A + (arow0 + r) * 512 + k0 + col, &sA[c * 8]);
      load_lds16(Wb + (long)(ncol0 + r) * 512 + k0 + col, &sBa[c * 8]);
      load_lds16(Wb + (long)(512 + ncol0 + r) * 512 + k0 + col, &sBg[c * 8]);
    }
    __syncthreads();
#pragma unroll
    for (int kf = 0; kf < 2; ++kf) {
      bf16x8 av[4], bav[4], bgv[4];
#pragma unroll
      for (int i = 0; i < 4; ++i) {
        av[i] = *(const bf16x8*)&sA[(wm + i * 16 + lr) * 64 + kf * 32 + kg * 8];
        bav[i] = *(const bf16x8*)&sBa[(wn + i * 16 + lr) * 64 + kf * 32 + kg * 8];
        bgv[i] = *(const bf16x8*)&sBg[(wn + i * 16 + lr) * 64 + kf * 32 + kg * 8];
      }
#pragma unroll
      for (int mi = 0; mi < 4; ++mi)
#pragma unroll
        for (int ni = 0; ni < 4; ++ni) {
          acc_a[mi][ni] = __builtin_amdgcn_mfma_f32_16x16x32_bf16(
              av[mi], bav[ni], acc_a[mi][ni], 0, 0, 0);
          acc_g[mi][ni] = __builtin_amdgcn_mfma_f32_16x16x32_bf16(
              av[mi], bgv[ni], acc_g[mi][ni], 0, 0, 0);
        }
    }
    __syncthreads();
  }
  int mg = kg * 4;
#pragma unroll
  for (int mi = 0; mi < 4; ++mi) {
#pragma unroll
    for (int ni = 0; ni < 4; ++ni) {
      int ncol = ncol0 + wn + ni * 16 + lr;
      float ba = b1[ncol], bg = b1[512 + ncol];
#pragma unroll
      for (int rgi = 0; rgi < 4; ++rgi) {
        long row = arow0 + wm + mi * 16 + mg + rgi;
        float a = acc_a[mi][ni][rgi] + ba;
        float gg = acc_g[mi][ni][rgi] + bg;
        float val = a / (1.f + __expf(-gg));
        X[row * 512 + ncol] = f2bf(val);
      }
    }
  }
}

// ---------------- depthwise conv + LN2 + SiLU ----------------
// grid (160, 32): tile<128 utt 16-step tiles (tiles 0..1 touch state);
// 128..143 rc h=0 (s=tile-128); 144..159 rc h=1 (s=tile-144).
// 512 threads, thread = channel d. Streaming: transient x, static FMA fan-out.
// Per-thread live set (31 w + 16 acc + transients) fits the 64-VGPR budget.
__global__ __launch_bounds__(512, 4) void k_conv_ln2(
    const u16* __restrict__ X, const float* __restrict__ state,
    const float* __restrict__ cwT, const float* __restrict__ cb,
    const float* __restrict__ g2, const float* __restrict__ bt2,
    u16* __restrict__ Z) {
  __shared__ float ys[16][512];
  __shared__ float stats[16][2];
  int d = threadIdx.x;
  int tile = blockIdx.x, b = blockIdx.y;

  float w[31];
#pragma unroll
  for (int k = 0; k < 31; ++k) w[k] = cwT[k * 512 + d];  // coalesced
  float cbd = cb[d];
  float acc[16];
#pragma unroll
  for (int r = 0; r < 16; ++r) acc[r] = cbd;

  const u16* Xc = X + (long)b * 512 + d;  // column base; row stride 16384 elems
  auto xrow = [&](long trow) -> float { return bf2f(Xc[trow * (long)(Bb * Dm)]); };
  auto step = [&](int j, float x) {
#pragma unroll
    for (int r = 0; r < 16; ++r) {
      int k = j - r;
      if (k >= 0 && k < 31) acc[r] += x * w[k];
    }
  };

  if (tile < 128) {
    long t0 = (long)tile * 16;
    if (tile < 2) {
      // window reaches before utterance start: per-element state-vs-X select
      const float* st = state + ((long)b * 512 + d) * 30;
#pragma unroll
      for (int j = 0; j < 46; ++j) {
        long tj = t0 - 30 + j;
        float x = (tj < 0) ? st[tj + 30] : xrow(Rr + tj);
        step(j, x);
        if ((j & 15) == 15) __builtin_amdgcn_sched_barrier(0);
      }
    } else {
      long r0 = (long)Rr + t0 - 30;
#pragma unroll
      for (int j = 0; j < 46; ++j) {
        step(j, xrow(r0 + j));
        if ((j & 15) == 15) __builtin_amdgcn_sched_barrier(0);
      }
    }
  } else if (tile < 144) {
    int s = tile - 128;
    long rp = (long)Rr + 128 * (s + 1) - 30;  // pads, j 0..29
    long rm = (long)32 * s - 30;              // body, j 30..45
#pragma unroll
    for (int j = 0; j < 30; ++j) {
      step(j, xrow(rp + j));
      if ((j & 15) == 15) __builtin_amdgcn_sched_barrier(0);
    }
#pragma unroll
    for (int j = 30; j < 46; ++j) step(j, xrow(rm + j));
  } else {
    int s = tile - 144;
    long rp = (long)Rr + 128 * (s + 1) - 14;  // pads, j 0..13
    long rm = (long)32 * s - 14;              // body, j 14..45
#pragma unroll
    for (int j = 0; j < 14; ++j) step(j, xrow(rp + j));
    __builtin_amdgcn_sched_barrier(0);
#pragma unroll
    for (int j = 14; j < 46; ++j) {
      step(j, xrow(rm + j));
      if ((j & 15) == 15) __builtin_amdgcn_sched_barrier(0);
    }
  }

#pragma unroll
  for (int r = 0; r < 16; ++r) ys[r][d] = acc[r];
  __syncthreads();

  int wid = d >> 6, lane = d & 63;
#pragma unroll
  for (int rr = 0; rr < 2; ++rr) {
    int r = wid * 2 + rr;
    float4 va = *(const float4*)&ys[r][lane * 8];
    float4 vb = *(const float4*)&ys[r][lane * 8 + 4];
    float s = va.x + va.y + va.z + va.w + vb.x + vb.y + vb.z + vb.w;
    float ss = va.x * va.x + va.y * va.y + va.z * va.z + va.w * va.w +
               vb.x * vb.x + vb.y * vb.y + vb.z * vb.z + vb.w * vb.w;
#pragma unroll
    for (int off = 1; off < 64; off <<= 1) {
      s += __shfl_xor(s, off);
      ss += __shfl_xor(ss, off);
    }
    if (lane == 0) {
      float mean = s * (1.f / 512.f);
      float var = ss * (1.f / 512.f) - mean * mean;
      stats[r][0] = mean;
      stats[r][1] = rsqrtf(var + 1e-5f);
    }
  }
  __syncthreads();

  float gg = g2[d], bb = bt2[d];
  long orow0;
  if (tile < 128) {
    orow0 = ((long)Rr + tile * 16) * Bb + b;
  } else if (tile < 144) {
    orow0 = (long)(32 * (tile - 128)) * Bb + b;
  } else {
    orow0 = (long)(32 * (tile - 144) + 16) * Bb + b;
  }
#pragma unroll
  for (int r = 0; r < 16; ++r) {
    float mean = stats[r][0], rstd = stats[r][1];
    float y = (acc[r] - mean) * rstd * gg + bb;
    float zz = y / (1.f + __expf(-y));
    Z[(orow0 + (long)r * Bb) * 512 + d] = f2bf(zz);
  }
}

// ---------------- GEMM2 + bias + residual (BK=64 double-buffer) ----------------
__global__ __launch_bounds__(256, 2) void k_gemm2(const u16* __restrict__ A,
                                                  const u16* __restrict__ Wb,
                                                  const float* __restrict__ b2,
                                                  const float* __restrict__ utt,
                                                  const float* __restrict__ rc,
                                                  float* __restrict__ out) {
  __shared__ __align__(16) u16 sA[2][128 * 64], sB[2][128 * 64];  // 64 KB
  int tid = threadIdx.x;
  int bid = blockIdx.x;
  int bm = bid >> 2, nt = bid & 3;  // A-panel sharers adjacent -> concurrent -> L3 reuse
  long arow0 = (long)bm * 128;
  int ncol0 = nt * 128;
  int lane = tid & 63, wid = tid >> 6;
  int wm = (wid >> 1) * 64, wn = (wid & 1) * 64;
  int lr = lane & 15, kg = lane >> 4;

  f32x4 acc[4][4];
#pragma unroll
  for (int i = 0; i < 4; ++i)
#pragma unroll
    for (int j = 0; j < 4; ++j) acc[i][j] = (f32x4)0.f;

  auto STAGE = [&](int buf, int k0) {
#pragma unroll
    for (int i = 0; i < 4; ++i) {
      int c = i * 256 + tid;
      int r = c >> 3, col = (c & 7) * 8;
      load_lds16(A + (arow0 + r) * 512 + k0 + col, &sA[buf][c * 8]);
      load_lds16(Wb + (long)(ncol0 + r) * 512 + k0 + col, &sB[buf][c * 8]);
    }
  };

  STAGE(0, 0);
  __syncthreads();
  for (int it = 0; it < 8; ++it) {
    int cur = it & 1;
    if (it < 7) STAGE(cur ^ 1, (it + 1) * 64);  // in flight across 32 MFMA + 16 ds_read
#pragma unroll
    for (int kf = 0; kf < 2; ++kf) {
      bf16x8 av[4], bv[4];
#pragma unroll
      for (int i = 0; i < 4; ++i) {
        av[i] = *(const bf16x8*)&sA[cur][(wm + i * 16 + lr) * 64 + kf * 32 + kg * 8];
        bv[i] = *(const bf16x8*)&sB[cur][(wn + i * 16 + lr) * 64 + kf * 32 + kg * 8];
      }
#pragma unroll
      for (int mi = 0; mi < 4; ++mi)
#pragma unroll
        for (int ni = 0; ni < 4; ++ni)
          acc[mi][ni] = __builtin_amdgcn_mfma_f32_16x16x32_bf16(
              av[mi], bv[ni], acc[mi][ni], 0, 0, 0);
    }
    __syncthreads();  // drains prefetch AFTER compute; one barrier/iter
  }
  int mg = kg * 4;
#pragma unroll
  for (int mi = 0; mi < 4; ++mi) {
#pragma unroll
    for (int ni = 0; ni < 4; ++ni) {
      int ncol = ncol0 + wn + ni * 16 + lr;
      float bv = b2[ncol];
#pragma unroll
      for (int rgi = 0; rgi < 4; ++rgi) {
        long row = arow0 + wm + mi * 16 + mg + rgi;  // tau
        float val = acc[mi][ni][rgi] + bv;
        const float* src = (row < 16384) ? rc + row * 512 : utt + (row - 16384) * 512;
        val += src[ncol];
        float* dst = (row < 16384) ? out + 33554432 + row * 512
                                   : out + (row - 16384) * 512;
        dst[ncol] = val;
      }
    }
  }
}

// ---------------- new_state ----------------
__global__ __launch_bounds__(256, 4) void k_state(const u16* __restrict__ X,
                                                  float* __restrict__ out) {
  int i = blockIdx.x * 256 + threadIdx.x;
  if (i >= 491520) return;
  int j = i % 30;
  int rest = i / 30;
  int d = rest & 511;
  int b = rest >> 9;
  out[41943040 + i] = bf2f(X[((long)(2530 + j) * Bb + b) * 512 + d]);
}

extern "C" void kernel_launch(void* const* d_in, const int* in_sizes, int n_in,
                              void* d_out, int out_size, void* d_ws, size_t ws_size,
                              hipStream_t stream) {
  const float* utt = (const float*)d_in[0];
  const float* rc = (const float*)d_in[1];
  const float* state = (const float*)d_in[2];
  const float* ln1g = (const float*)d_in[3];
  const float* ln1b = (const float*)d_in[4];
  const float* w1 = (const float*)d_in[5];
  const float* b1 = (const float*)d_in[6];
  const float* cw = (const float*)d_in[7];
  const float* cb = (const float*)d_in[8];
  const float* ln2g = (const float*)d_in[9];
  const float* ln2b = (const float*)d_in[10];
  const float* w2 = (const float*)d_in[11];
  const float* b2 = (const float*)d_in[12];
  float* out = (float*)d_out;

  char* ws = (char*)d_ws;
  u16* w1b = (u16*)ws;                                         // 1 MB
  u16* w2b = (u16*)(ws + (1 << 20));                           // 512 KB
  float* cwT = (float*)(ws + (1 << 20) + (1 << 19));           // 64 KB
  u16* lnx = (u16*)(ws + (1 << 20) + (1 << 19) + (1 << 16));   // 80 MiB (ln_x, later z)
  u16* xbuf = lnx + (size_t)MROWS * Dm;                        // 80 MiB

  k_cast<<<512, 256, 0, stream>>>(w1, w1b, 1024 * 512);
  k_cast<<<256, 256, 0, stream>>>(w2, w2b, 512 * 512);
  k_wt<<<62, 256, 0, stream>>>(cw, cwT);
  k_ln1<<<MROWS / 4, 256, 0, stream>>>(utt, rc, ln1g, ln1b, lnx);
  k_gemm1<<<2560, 256, 0, stream>>>(lnx, w1b, b1, xbuf);
  k_conv_ln2<<<dim3(160, 32), 512, 0, stream>>>(xbuf, state, cwT, cb, ln2g, ln2b, lnx);
  k_gemm2<<<2560, 256, 0, stream>>>(lnx, w2b, b2, utt, rc, out);
  k_state<<<1920, 256, 0, stream>>>(xbuf, out);
}

// Round 10
// 380.164 us; speedup vs baseline: 1.1318x; 1.0355x over previous
//
#include <hip/hip_runtime.h>

// Emformer convolution module, MI355X/gfx950.
// Pipeline: cast weights -> LN1 -> GEMM1+GLU (bf16 MFMA) -> dwconv+LN2+SiLU -> GEMM2+residual -> state.
// R7 LESSON: __syncthreads drains vmcnt(0); %640 decode thrashes L3.
// R8 LESSON: BK=64 dbuf halves occupancy (VGPR 128, LDS 64KB) -> slower than 1-phase + TLP. Reverted.
// R9: gemm2 = R6 1-phase BK=64 + >>2 decode. conv = LDS-staged X window:
//     46 rows staged via global_load_lds (1 instr/row/block), inner loop ds_read_u16 with
//     static offsets (zero address math), ys aliased onto stage buffer (47KB -> 3 blocks/CU).

#define Dm 512
#define STATE 30
#define Uu 2048
#define Rr 512
#define Bb 32
#define Tt 2560        // Rr + Uu
#define MROWS 81920    // Tt * Bb

typedef unsigned short u16;
typedef unsigned int u32;
typedef __attribute__((ext_vector_type(8))) __bf16 bf16x8;
typedef __attribute__((ext_vector_type(4))) float f32x4;

__device__ __forceinline__ u16 f2bf(float x) {
  u32 u = __float_as_uint(x);
  u += 0x7fff + ((u >> 16) & 1);   // RNE
  return (u16)(u >> 16);
}
__device__ __forceinline__ float bf2f(u16 h) {
  return __uint_as_float((u32)h << 16);
}
__device__ __forceinline__ void load_lds16(const void* g, void* l) {
  __builtin_amdgcn_global_load_lds(
      (const __attribute__((address_space(1))) void*)g,
      (__attribute__((address_space(3))) void*)l, 16, 0, 0);
}

// ---------------- cast f32 -> bf16 (weights) ----------------
__global__ __launch_bounds__(256, 4) void k_cast(const float* __restrict__ src,
                                                 u16* __restrict__ dst, int n) {
  int i = (blockIdx.x * 256 + threadIdx.x) * 4;
  if (i >= n) return;
  float4 v = *(const float4*)(src + i);
  u32 lo = (u32)f2bf(v.x) | ((u32)f2bf(v.y) << 16);
  u32 hi = (u32)f2bf(v.z) | ((u32)f2bf(v.w) << 16);
  *(uint2*)(dst + i) = make_uint2(lo, hi);
}

// ---------------- transpose conv weight: cw[512][31] -> cwT[31][512] ----------------
__global__ __launch_bounds__(256, 4) void k_wt(const float* __restrict__ cw,
                                               float* __restrict__ cwT) {
  int i = blockIdx.x * 256 + threadIdx.x;
  if (i >= 31 * 512) return;
  int k = i >> 9, d = i & 511;
  cwT[i] = cw[d * 31 + k];
}

// ---------------- LN1: concat(rc, utt) -> bf16 ----------------
__global__ __launch_bounds__(256, 4) void k_ln1(const float* __restrict__ utt,
                                                const float* __restrict__ rc,
                                                const float* __restrict__ g,
                                                const float* __restrict__ b,
                                                u16* __restrict__ out) {
  int wid = threadIdx.x >> 6, lane = threadIdx.x & 63;
  long row = (long)blockIdx.x * 4 + wid;  // token index tau = t*B + b
  const float* src = (row < (long)Rr * Bb) ? rc + row * Dm
                                           : utt + (row - (long)Rr * Bb) * Dm;
  int d0 = lane * 8;
  float4 v0 = *(const float4*)(src + d0);
  float4 v1 = *(const float4*)(src + d0 + 4);
  float s = v0.x + v0.y + v0.z + v0.w + v1.x + v1.y + v1.z + v1.w;
  float ss = v0.x * v0.x + v0.y * v0.y + v0.z * v0.z + v0.w * v0.w +
             v1.x * v1.x + v1.y * v1.y + v1.z * v1.z + v1.w * v1.w;
#pragma unroll
  for (int off = 1; off < 64; off <<= 1) {
    s += __shfl_xor(s, off);
    ss += __shfl_xor(ss, off);
  }
  float mean = s * (1.f / 512.f);
  float var = ss * (1.f / 512.f) - mean * mean;
  float rstd = rsqrtf(var + 1e-5f);
  float4 g0 = *(const float4*)(g + d0);
  float4 g1 = *(const float4*)(g + d0 + 4);
  float4 b0 = *(const float4*)(b + d0);
  float4 b1v = *(const float4*)(b + d0 + 4);
  float o[8];
  o[0] = (v0.x - mean) * rstd * g0.x + b0.x;
  o[1] = (v0.y - mean) * rstd * g0.y + b0.y;
  o[2] = (v0.z - mean) * rstd * g0.z + b0.z;
  o[3] = (v0.w - mean) * rstd * g0.w + b0.w;
  o[4] = (v1.x - mean) * rstd * g1.x + b1v.x;
  o[5] = (v1.y - mean) * rstd * g1.y + b1v.y;
  o[6] = (v1.z - mean) * rstd * g1.z + b1v.z;
  o[7] = (v1.w - mean) * rstd * g1.w + b1v.w;
  u32 p[4];
#pragma unroll
  for (int i = 0; i < 4; ++i)
    p[i] = (u32)f2bf(o[2 * i]) | ((u32)f2bf(o[2 * i + 1]) << 16);
  *(uint4*)(out + row * Dm + d0) = make_uint4(p[0], p[1], p[2], p[3]);
}

// ---------------- GEMM1 + GLU (1-phase BK=64) ----------------
__global__ __launch_bounds__(256, 2) void k_gemm1(const u16* __restrict__ A,
                                                  const u16* __restrict__ Wb,
                                                  const float* __restrict__ b1,
                                                  u16* __restrict__ X) {
  __shared__ __align__(16) u16 sA[128 * 64], sBa[128 * 64], sBg[128 * 64];
  int tid = threadIdx.x;
  int bid = blockIdx.x;
  int bm = bid >> 2, nt = bid & 3;  // A-panel sharers adjacent -> concurrent -> L3 reuse
  long arow0 = (long)bm * 128;
  int ncol0 = nt * 128;
  int lane = tid & 63, wid = tid >> 6;
  int wm = (wid >> 1) * 64, wn = (wid & 1) * 64;
  int lr = lane & 15, kg = lane >> 4;

  f32x4 acc_a[4][4], acc_g[4][4];
#pragma unroll
  for (int i = 0; i < 4; ++i)
#pragma unroll
    for (int j = 0; j < 4; ++j) {
      acc_a[i][j] = (f32x4)0.f;
      acc_g[i][j] = (f32x4)0.f;
    }

  for (int k0 = 0; k0 < 512; k0 += 64) {
#pragma unroll
    for (int i = 0; i < 4; ++i) {
      int c = i * 256 + tid;
      int r = c >> 3, col = (c & 7) * 8;
      load_lds16(A + (arow0 + r) * 512 + k0 + col, &sA[c * 8]);
      load_lds16(Wb + (long)(ncol0 + r) * 512 + k0 + col, &sBa[c * 8]);
      load_lds16(Wb + (long)(512 + ncol0 + r) * 512 + k0 + col, &sBg[c * 8]);
    }
    __syncthreads();
#pragma unroll
    for (int kf = 0; kf < 2; ++kf) {
      bf16x8 av[4], bav[4], bgv[4];
#pragma unroll
      for (int i = 0; i < 4; ++i) {
        av[i] = *(const bf16x8*)&sA[(wm + i * 16 + lr) * 64 + kf * 32 + kg * 8];
        bav[i] = *(const bf16x8*)&sBa[(wn + i * 16 + lr) * 64 + kf * 32 + kg * 8];
        bgv[i] = *(const bf16x8*)&sBg[(wn + i * 16 + lr) * 64 + kf * 32 + kg * 8];
      }
#pragma unroll
      for (int mi = 0; mi < 4; ++mi)
#pragma unroll
        for (int ni = 0; ni < 4; ++ni) {
          acc_a[mi][ni] = __builtin_amdgcn_mfma_f32_16x16x32_bf16(
              av[mi], bav[ni], acc_a[mi][ni], 0, 0, 0);
          acc_g[mi][ni] = __builtin_amdgcn_mfma_f32_16x16x32_bf16(
              av[mi], bgv[ni], acc_g[mi][ni], 0, 0, 0);
        }
    }
    __syncthreads();
  }
  int mg = kg * 4;
#pragma unroll
  for (int mi = 0; mi < 4; ++mi) {
#pragma unroll
    for (int ni = 0; ni < 4; ++ni) {
      int ncol = ncol0 + wn + ni * 16 + lr;
      float ba = b1[ncol], bg = b1[512 + ncol];
#pragma unroll
      for (int rgi = 0; rgi < 4; ++rgi) {
        long row = arow0 + wm + mi * 16 + mg + rgi;
        float a = acc_a[mi][ni][rgi] + ba;
        float gg = acc_g[mi][ni][rgi] + bg;
        float val = a / (1.f + __expf(-gg));
        X[row * 512 + ncol] = f2bf(val);
      }
    }
  }
}

// ---------------- depthwise conv + LN2 + SiLU (LDS-staged X window) ----------------
// grid (160, 32): tile<128 utt 16-step tiles (tiles 0..1 fallback: state window);
// 128..143 rc h=0 (s=tile-128); 144..159 rc h=1 (s=tile-144).
// 512 threads, thread = channel d. X window (46 rows x 512ch bf16) staged to LDS by
// global_load_lds (1 instr per 1KB row); inner loop = ds_read_u16 static offsets + FMA.
// ys for LN2 aliases the stage buffer after a barrier. LDS ~47KB -> 3 blocks/CU.
__global__ __launch_bounds__(512, 2) void k_conv_ln2(
    const u16* __restrict__ X, const float* __restrict__ state,
    const float* __restrict__ cwT, const float* __restrict__ cb,
    const float* __restrict__ g2, const float* __restrict__ bt2,
    u16* __restrict__ Z) {
  __shared__ __align__(16) u16 stX[46 * 512];   // 47104 B; later aliased as ys[16][512] f32
  __shared__ float stats[16][2];
  float* ys = (float*)stX;

  int d = threadIdx.x;
  int tile = blockIdx.x, b = blockIdx.y;
  int wv = d >> 6, ln = d & 63;

  float w[31];
#pragma unroll
  for (int k = 0; k < 31; ++k) w[k] = cwT[k * 512 + d];  // coalesced
  float cbd = cb[d];
  float acc[16];
#pragma unroll
  for (int r = 0; r < 16; ++r) acc[r] = cbd;

  auto step = [&](int j, float x) {
#pragma unroll
    for (int r = 0; r < 16; ++r) {
      int k = j - r;
      if (k >= 0 && k < 31) acc[r] += x * w[k];
    }
  };

  const u16* Xb = X + (long)b * 512;  // + trow*16384 + col

  if (tile >= 2) {
    // ---- stage 46 rows: wave wv handles rows wv, wv+8, ... (1KB each) ----
    if (tile < 128) {
      long base = (long)Rr + tile * 16 - 30;
      for (int r = wv; r < 46; r += 8)
        load_lds16(Xb + (base + r) * 16384 + ln * 8, &stX[r * 512 + ln * 8]);
    } else if (tile < 144) {
      int s = tile - 128;
      for (int r = wv; r < 46; r += 8) {
        long trow = (r < 30) ? ((long)Rr + 128 * (s + 1) - 30 + r)
                             : ((long)32 * s + r - 30);
        load_lds16(Xb + trow * 16384 + ln * 8, &stX[r * 512 + ln * 8]);
      }
    } else {
      int s = tile - 144;
      for (int r = wv; r < 46; r += 8) {
        long trow = (r < 14) ? ((long)Rr + 128 * (s + 1) - 14 + r)
                             : ((long)32 * s + r - 14);
        load_lds16(Xb + trow * 16384 + ln * 8, &stX[r * 512 + ln * 8]);
      }
    }
    __syncthreads();  // stage complete
    // ---- consume: static LDS offsets, zero address math ----
#pragma unroll
    for (int j = 0; j < 46; ++j) {
      float x = bf2f(stX[j * 512 + d]);
      step(j, x);
      if ((j & 7) == 7) __builtin_amdgcn_sched_barrier(0);
    }
  } else {
    // tiles 0..1: window reaches before utterance start -> per-element state-vs-X select
    long t0 = (long)tile * 16;
    const float* st = state + ((long)b * 512 + d) * 30;
    const u16* Xc = X + (long)b * 512 + d;
#pragma unroll
    for (int j = 0; j < 46; ++j) {
      long tj = t0 - 30 + j;
      float x = (tj < 0) ? st[tj + 30]
                         : bf2f(Xc[((long)Rr + tj) * 16384]);
      step(j, x);
      if ((j & 15) == 15) __builtin_amdgcn_sched_barrier(0);
    }
  }

  __syncthreads();  // all stX reads done before ys overwrites it
#pragma unroll
  for (int r = 0; r < 16; ++r) ys[r * 512 + d] = acc[r];
  __syncthreads();

#pragma unroll
  for (int rr = 0; rr < 2; ++rr) {
    int r = wv * 2 + rr;
    float4 va = *(const float4*)&ys[r * 512 + ln * 8];
    float4 vb = *(const float4*)&ys[r * 512 + ln * 8 + 4];
    float s = va.x + va.y + va.z + va.w + vb.x + vb.y + vb.z + vb.w;
    float ss = va.x * va.x + va.y * va.y + va.z * va.z + va.w * va.w +
               vb.x * vb.x + vb.y * vb.y + vb.z * vb.z + vb.w * vb.w;
#pragma unroll
    for (int off = 1; off < 64; off <<= 1) {
      s += __shfl_xor(s, off);
      ss += __shfl_xor(ss, off);
    }
    if (ln == 0) {
      float mean = s * (1.f / 512.f);
      float var = ss * (1.f / 512.f) - mean * mean;
      stats[r][0] = mean;
      stats[r][1] = rsqrtf(var + 1e-5f);
    }
  }
  __syncthreads();

  float gg = g2[d], bb = bt2[d];
  long orow0;
  if (tile < 128) {
    orow0 = ((long)Rr + tile * 16) * Bb + b;
  } else if (tile < 144) {
    orow0 = (long)(32 * (tile - 128)) * Bb + b;
  } else {
    orow0 = (long)(32 * (tile - 144) + 16) * Bb + b;
  }
#pragma unroll
  for (int r = 0; r < 16; ++r) {
    float mean = stats[r][0], rstd = stats[r][1];
    float y = (acc[r] - mean) * rstd * gg + bb;
    float zz = y / (1.f + __expf(-y));
    Z[(orow0 + (long)r * Bb) * 512 + d] = f2bf(zz);
  }
}

// ---------------- GEMM2 + bias + residual (1-phase BK=64, R6-verified) ----------------
__global__ __launch_bounds__(256, 2) void k_gemm2(const u16* __restrict__ A,
                                                  const u16* __restrict__ Wb,
                                                  const float* __restrict__ b2,
                                                  const float* __restrict__ utt,
                                                  const float* __restrict__ rc,
                                                  float* __restrict__ out) {
  __shared__ __align__(16) u16 sA[128 * 64], sB[128 * 64];
  int tid = threadIdx.x;
  int bid = blockIdx.x;
  int bm = bid >> 2, nt = bid & 3;  // A-panel sharers adjacent -> concurrent -> L3 reuse
  long arow0 = (long)bm * 128;
  int ncol0 = nt * 128;
  int lane = tid & 63, wid = tid >> 6;
  int wm = (wid >> 1) * 64, wn = (wid & 1) * 64;
  int lr = lane & 15, kg = lane >> 4;

  f32x4 acc[4][4];
#pragma unroll
  for (int i = 0; i < 4; ++i)
#pragma unroll
    for (int j = 0; j < 4; ++j) acc[i][j] = (f32x4)0.f;

  for (int k0 = 0; k0 < 512; k0 += 64) {
#pragma unroll
    for (int i = 0; i < 4; ++i) {
      int c = i * 256 + tid;
      int r = c >> 3, col = (c & 7) * 8;
      load_lds16(A + (arow0 + r) * 512 + k0 + col, &sA[c * 8]);
      load_lds16(Wb + (long)(ncol0 + r) * 512 + k0 + col, &sB[c * 8]);
    }
    __syncthreads();
#pragma unroll
    for (int kf = 0; kf < 2; ++kf) {
      bf16x8 av[4], bv[4];
#pragma unroll
      for (int i = 0; i < 4; ++i) {
        av[i] = *(const bf16x8*)&sA[(wm + i * 16 + lr) * 64 + kf * 32 + kg * 8];
        bv[i] = *(const bf16x8*)&sB[(wn + i * 16 + lr) * 64 + kf * 32 + kg * 8];
      }
#pragma unroll
      for (int mi = 0; mi < 4; ++mi)
#pragma unroll
        for (int ni = 0; ni < 4; ++ni)
          acc[mi][ni] = __builtin_amdgcn_mfma_f32_16x16x32_bf16(
              av[mi], bv[ni], acc[mi][ni], 0, 0, 0);
    }
    __syncthreads();
  }
  int mg = kg * 4;
#pragma unroll
  for (int mi = 0; mi < 4; ++mi) {
#pragma unroll
    for (int ni = 0; ni < 4; ++ni) {
      int ncol = ncol0 + wn + ni * 16 + lr;
      float bv = b2[ncol];
#pragma unroll
      for (int rgi = 0; rgi < 4; ++rgi) {
        long row = arow0 + wm + mi * 16 + mg + rgi;  // tau
        float val = acc[mi][ni][rgi] + bv;
        const float* src = (row < 16384) ? rc + row * 512 : utt + (row - 16384) * 512;
        val += src[ncol];
        float* dst = (row < 16384) ? out + 33554432 + row * 512
                                   : out + (row - 16384) * 512;
        dst[ncol] = val;
      }
    }
  }
}

// ---------------- new_state ----------------
__global__ __launch_bounds__(256, 4) void k_state(const u16* __restrict__ X,
                                                  float* __restrict__ out) {
  int i = blockIdx.x * 256 + threadIdx.x;
  if (i >= 491520) return;
  int j = i % 30;
  int rest = i / 30;
  int d = rest & 511;
  int b = rest >> 9;
  out[41943040 + i] = bf2f(X[((long)(2530 + j) * Bb + b) * 512 + d]);
}

extern "C" void kernel_launch(void* const* d_in, const int* in_sizes, int n_in,
                              void* d_out, int out_size, void* d_ws, size_t ws_size,
                              hipStream_t stream) {
  const float* utt = (const float*)d_in[0];
  const float* rc = (const float*)d_in[1];
  const float* state = (const float*)d_in[2];
  const float* ln1g = (const float*)d_in[3];
  const float* ln1b = (const float*)d_in[4];
  const float* w1 = (const float*)d_in[5];
  const float* b1 = (const float*)d_in[6];
  const float* cw = (const float*)d_in[7];
  const float* cb = (const float*)d_in[8];
  const float* ln2g = (const float*)d_in[9];
  const float* ln2b = (const float*)d_in[10];
  const float* w2 = (const float*)d_in[11];
  const float* b2 = (const float*)d_in[12];
  float* out = (float*)d_out;

  char* ws = (char*)d_ws;
  u16* w1b = (u16*)ws;                                         // 1 MB
  u16* w2b = (u16*)(ws + (1 << 20));                           // 512 KB
  float* cwT = (float*)(ws + (1 << 20) + (1 << 19));           // 64 KB
  u16* lnx = (u16*)(ws + (1 << 20) + (1 << 19) + (1 << 16));   // 80 MiB (ln_x, later z)
  u16* xbuf = lnx + (size_t)MROWS * Dm;                        // 80 MiB

  k_cast<<<512, 256, 0, stream>>>(w1, w1b, 1024 * 512);
  k_cast<<<256, 256, 0, stream>>>(w2, w2b, 512 * 512);
  k_wt<<<62, 256, 0, stream>>>(cw, cwT);
  k_ln1<<<MROWS / 4, 256, 0, stream>>>(utt, rc, ln1g, ln1b, lnx);
  k_gemm1<<<2560, 256, 0, stream>>>(lnx, w1b, b1, xbuf);
  k_conv_ln2<<<dim3(160, 32), 512, 0, stream>>>(xbuf, state, cwT, cb, ln2g, ln2b, lnx);
  k_gemm2<<<2560, 256, 0, stream>>>(lnx, w2b, b2, utt, rc, out);
  k_state<<<1920, 256, 0, stream>>>(xbuf, out);
}

// Round 11
// 371.513 us; speedup vs baseline: 1.1581x; 1.0233x over previous
//
#include <hip/hip_runtime.h>

// Emformer convolution module, MI355X/gfx950.
// Pipeline: cast weights -> LN1 -> GEMM1+GLU (bf16 MFMA) -> dwconv+LN2+SiLU -> GEMM2+residual -> state.
// R7: __syncthreads drains vmcnt(0). R8: dbuf halves occupancy -> TLP wins. R9: conv LDS-staged.
// R10: GEMM LDS bank-conflict fix (T2): fragment reads had 16 lanes on one 4-bank set
//   (row stride 128B = 32 banks). Pre-swizzled global SOURCE column (slot c <- unit (c&7)^(r&7))
//   + swizzled read unit (U^(lr&7)); LDS dest stays linear (global_load_lds requirement).

#define Dm 512
#define STATE 30
#define Uu 2048
#define Rr 512
#define Bb 32
#define Tt 2560        // Rr + Uu
#define MROWS 81920    // Tt * Bb

typedef unsigned short u16;
typedef unsigned int u32;
typedef __attribute__((ext_vector_type(8))) __bf16 bf16x8;
typedef __attribute__((ext_vector_type(4))) float f32x4;

__device__ __forceinline__ u16 f2bf(float x) {
  u32 u = __float_as_uint(x);
  u += 0x7fff + ((u >> 16) & 1);   // RNE
  return (u16)(u >> 16);
}
__device__ __forceinline__ float bf2f(u16 h) {
  return __uint_as_float((u32)h << 16);
}
__device__ __forceinline__ void load_lds16(const void* g, void* l) {
  __builtin_amdgcn_global_load_lds(
      (const __attribute__((address_space(1))) void*)g,
      (__attribute__((address_space(3))) void*)l, 16, 0, 0);
}

// ---------------- cast f32 -> bf16 (weights) ----------------
__global__ __launch_bounds__(256, 4) void k_cast(const float* __restrict__ src,
                                                 u16* __restrict__ dst, int n) {
  int i = (blockIdx.x * 256 + threadIdx.x) * 4;
  if (i >= n) return;
  float4 v = *(const float4*)(src + i);
  u32 lo = (u32)f2bf(v.x) | ((u32)f2bf(v.y) << 16);
  u32 hi = (u32)f2bf(v.z) | ((u32)f2bf(v.w) << 16);
  *(uint2*)(dst + i) = make_uint2(lo, hi);
}

// ---------------- transpose conv weight: cw[512][31] -> cwT[31][512] ----------------
__global__ __launch_bounds__(256, 4) void k_wt(const float* __restrict__ cw,
                                               float* __restrict__ cwT) {
  int i = blockIdx.x * 256 + threadIdx.x;
  if (i >= 31 * 512) return;
  int k = i >> 9, d = i & 511;
  cwT[i] = cw[d * 31 + k];
}

// ---------------- LN1: concat(rc, utt) -> bf16 ----------------
__global__ __launch_bounds__(256, 4) void k_ln1(const float* __restrict__ utt,
                                                const float* __restrict__ rc,
                                                const float* __restrict__ g,
                                                const float* __restrict__ b,
                                                u16* __restrict__ out) {
  int wid = threadIdx.x >> 6, lane = threadIdx.x & 63;
  long row = (long)blockIdx.x * 4 + wid;  // token index tau = t*B + b
  const float* src = (row < (long)Rr * Bb) ? rc + row * Dm
                                           : utt + (row - (long)Rr * Bb) * Dm;
  int d0 = lane * 8;
  float4 v0 = *(const float4*)(src + d0);
  float4 v1 = *(const float4*)(src + d0 + 4);
  float s = v0.x + v0.y + v0.z + v0.w + v1.x + v1.y + v1.z + v1.w;
  float ss = v0.x * v0.x + v0.y * v0.y + v0.z * v0.z + v0.w * v0.w +
             v1.x * v1.x + v1.y * v1.y + v1.z * v1.z + v1.w * v1.w;
#pragma unroll
  for (int off = 1; off < 64; off <<= 1) {
    s += __shfl_xor(s, off);
    ss += __shfl_xor(ss, off);
  }
  float mean = s * (1.f / 512.f);
  float var = ss * (1.f / 512.f) - mean * mean;
  float rstd = rsqrtf(var + 1e-5f);
  float4 g0 = *(const float4*)(g + d0);
  float4 g1 = *(const float4*)(g + d0 + 4);
  float4 b0 = *(const float4*)(b + d0);
  float4 b1v = *(const float4*)(b + d0 + 4);
  float o[8];
  o[0] = (v0.x - mean) * rstd * g0.x + b0.x;
  o[1] = (v0.y - mean) * rstd * g0.y + b0.y;
  o[2] = (v0.z - mean) * rstd * g0.z + b0.z;
  o[3] = (v0.w - mean) * rstd * g0.w + b0.w;
  o[4] = (v1.x - mean) * rstd * g1.x + b1v.x;
  o[5] = (v1.y - mean) * rstd * g1.y + b1v.y;
  o[6] = (v1.z - mean) * rstd * g1.z + b1v.z;
  o[7] = (v1.w - mean) * rstd * g1.w + b1v.w;
  u32 p[4];
#pragma unroll
  for (int i = 0; i < 4; ++i)
    p[i] = (u32)f2bf(o[2 * i]) | ((u32)f2bf(o[2 * i + 1]) << 16);
  *(uint4*)(out + row * Dm + d0) = make_uint4(p[0], p[1], p[2], p[3]);
}

// ---------------- GEMM1 + GLU (1-phase BK=64, swizzled LDS) ----------------
__global__ __launch_bounds__(256, 2) void k_gemm1(const u16* __restrict__ A,
                                                  const u16* __restrict__ Wb,
                                                  const float* __restrict__ b1,
                                                  u16* __restrict__ X) {
  __shared__ __align__(16) u16 sA[128 * 64], sBa[128 * 64], sBg[128 * 64];
  int tid = threadIdx.x;
  int bid = blockIdx.x;
  int bm = bid >> 2, nt = bid & 3;
  long arow0 = (long)bm * 128;
  int ncol0 = nt * 128;
  int lane = tid & 63, wid = tid >> 6;
  int wm = (wid >> 1) * 64, wn = (wid & 1) * 64;
  int lr = lane & 15, kg = lane >> 4;
  int l7 = lr & 7;

  f32x4 acc_a[4][4], acc_g[4][4];
#pragma unroll
  for (int i = 0; i < 4; ++i)
#pragma unroll
    for (int j = 0; j < 4; ++j) {
      acc_a[i][j] = (f32x4)0.f;
      acc_g[i][j] = (f32x4)0.f;
    }

  for (int k0 = 0; k0 < 512; k0 += 64) {
#pragma unroll
    for (int i = 0; i < 4; ++i) {
      int c = i * 256 + tid;
      int r = c >> 3;
      int col = ((c & 7) ^ (r & 7)) * 8;  // pre-swizzled source column
      load_lds16(A + (arow0 + r) * 512 + k0 + col, &sA[c * 8]);
      load_lds16(Wb + (long)(ncol0 + r) * 512 + k0 + col, &sBa[c * 8]);
      load_lds16(Wb + (long)(512 + ncol0 + r) * 512 + k0 + col, &sBg[c * 8]);
    }
    __syncthreads();
#pragma unroll
    for (int kf = 0; kf < 2; ++kf) {
      int u = (kf * 4 + kg) ^ l7;  // swizzled read unit
      bf16x8 av[4], bav[4], bgv[4];
#pragma unroll
      for (int i = 0; i < 4; ++i) {
        av[i] = *(const bf16x8*)&sA[(wm + i * 16 + lr) * 64 + u * 8];
        bav[i] = *(const bf16x8*)&sBa[(wn + i * 16 + lr) * 64 + u * 8];
        bgv[i] = *(const bf16x8*)&sBg[(wn + i * 16 + lr) * 64 + u * 8];
      }
#pragma unroll
      for (int mi = 0; mi < 4; ++mi)
#pragma unroll
        for (int ni = 0; ni < 4; ++ni) {
          acc_a[mi][ni] = __builtin_amdgcn_mfma_f32_16x16x32_bf16(
              av[mi], bav[ni], acc_a[mi][ni], 0, 0, 0);
          acc_g[mi][ni] = __builtin_amdgcn_mfma_f32_16x16x32_bf16(
              av[mi], bgv[ni], acc_g[mi][ni], 0, 0, 0);
        }
    }
    __syncthreads();
  }
  int mg = kg * 4;
#pragma unroll
  for (int mi = 0; mi < 4; ++mi) {
#pragma unroll
    for (int ni = 0; ni < 4; ++ni) {
      int ncol = ncol0 + wn + ni * 16 + lr;
      float ba = b1[ncol], bg = b1[512 + ncol];
#pragma unroll
      for (int rgi = 0; rgi < 4; ++rgi) {
        long row = arow0 + wm + mi * 16 + mg + rgi;
        float a = acc_a[mi][ni][rgi] + ba;
        float gg = acc_g[mi][ni][rgi] + bg;
        float val = a / (1.f + __expf(-gg));
        X[row * 512 + ncol] = f2bf(val);
      }
    }
  }
}

// ---------------- depthwise conv + LN2 + SiLU (LDS-staged X window) ----------------
__global__ __launch_bounds__(512, 2) void k_conv_ln2(
    const u16* __restrict__ X, const float* __restrict__ state,
    const float* __restrict__ cwT, const float* __restrict__ cb,
    const float* __restrict__ g2, const float* __restrict__ bt2,
    u16* __restrict__ Z) {
  __shared__ __align__(16) u16 stX[46 * 512];   // 47104 B; later aliased as ys[16][512] f32
  __shared__ float stats[16][2];
  float* ys = (float*)stX;

  int d = threadIdx.x;
  int tile = blockIdx.x, b = blockIdx.y;
  int wv = d >> 6, ln = d & 63;

  float w[31];
#pragma unroll
  for (int k = 0; k < 31; ++k) w[k] = cwT[k * 512 + d];  // coalesced
  float cbd = cb[d];
  float acc[16];
#pragma unroll
  for (int r = 0; r < 16; ++r) acc[r] = cbd;

  auto step = [&](int j, float x) {
#pragma unroll
    for (int r = 0; r < 16; ++r) {
      int k = j - r;
      if (k >= 0 && k < 31) acc[r] += x * w[k];
    }
  };

  const u16* Xb = X + (long)b * 512;  // + trow*16384 + col

  if (tile >= 2) {
    if (tile < 128) {
      long base = (long)Rr + tile * 16 - 30;
      for (int r = wv; r < 46; r += 8)
        load_lds16(Xb + (base + r) * 16384 + ln * 8, &stX[r * 512 + ln * 8]);
    } else if (tile < 144) {
      int s = tile - 128;
      for (int r = wv; r < 46; r += 8) {
        long trow = (r < 30) ? ((long)Rr + 128 * (s + 1) - 30 + r)
                             : ((long)32 * s + r - 30);
        load_lds16(Xb + trow * 16384 + ln * 8, &stX[r * 512 + ln * 8]);
      }
    } else {
      int s = tile - 144;
      for (int r = wv; r < 46; r += 8) {
        long trow = (r < 14) ? ((long)Rr + 128 * (s + 1) - 14 + r)
                             : ((long)32 * s + r - 14);
        load_lds16(Xb + trow * 16384 + ln * 8, &stX[r * 512 + ln * 8]);
      }
    }
    __syncthreads();
#pragma unroll
    for (int j = 0; j < 46; ++j) {
      float x = bf2f(stX[j * 512 + d]);
      step(j, x);
      if ((j & 7) == 7) __builtin_amdgcn_sched_barrier(0);
    }
  } else {
    long t0 = (long)tile * 16;
    const float* st = state + ((long)b * 512 + d) * 30;
    const u16* Xc = X + (long)b * 512 + d;
#pragma unroll
    for (int j = 0; j < 46; ++j) {
      long tj = t0 - 30 + j;
      float x = (tj < 0) ? st[tj + 30]
                         : bf2f(Xc[((long)Rr + tj) * 16384]);
      step(j, x);
      if ((j & 15) == 15) __builtin_amdgcn_sched_barrier(0);
    }
  }

  __syncthreads();
#pragma unroll
  for (int r = 0; r < 16; ++r) ys[r * 512 + d] = acc[r];
  __syncthreads();

#pragma unroll
  for (int rr = 0; rr < 2; ++rr) {
    int r = wv * 2 + rr;
    float4 va = *(const float4*)&ys[r * 512 + ln * 8];
    float4 vb = *(const float4*)&ys[r * 512 + ln * 8 + 4];
    float s = va.x + va.y + va.z + va.w + vb.x + vb.y + vb.z + vb.w;
    float ss = va.x * va.x + va.y * va.y + va.z * va.z + va.w * va.w +
               vb.x * vb.x + vb.y * vb.y + vb.z * vb.z + vb.w * vb.w;
#pragma unroll
    for (int off = 1; off < 64; off <<= 1) {
      s += __shfl_xor(s, off);
      ss += __shfl_xor(ss, off);
    }
    if (ln == 0) {
      float mean = s * (1.f / 512.f);
      float var = ss * (1.f / 512.f) - mean * mean;
      stats[r][0] = mean;
      stats[r][1] = rsqrtf(var + 1e-5f);
    }
  }
  __syncthreads();

  float gg = g2[d], bb = bt2[d];
  long orow0;
  if (tile < 128) {
    orow0 = ((long)Rr + tile * 16) * Bb + b;
  } else if (tile < 144) {
    orow0 = (long)(32 * (tile - 128)) * Bb + b;
  } else {
    orow0 = (long)(32 * (tile - 144) + 16) * Bb + b;
  }
#pragma unroll
  for (int r = 0; r < 16; ++r) {
    float mean = stats[r][0], rstd = stats[r][1];
    float y = (acc[r] - mean) * rstd * gg + bb;
    float zz = y / (1.f + __expf(-y));
    Z[(orow0 + (long)r * Bb) * 512 + d] = f2bf(zz);
  }
}

// ---------------- GEMM2 + bias + residual (1-phase BK=64, swizzled LDS) ----------------
__global__ __launch_bounds__(256, 2) void k_gemm2(const u16* __restrict__ A,
                                                  const u16* __restrict__ Wb,
                                                  const float* __restrict__ b2,
                                                  const float* __restrict__ utt,
                                                  const float* __restrict__ rc,
                                                  float* __restrict__ out) {
  __shared__ __align__(16) u16 sA[128 * 64], sB[128 * 64];
  int tid = threadIdx.x;
  int bid = blockIdx.x;
  int bm = bid >> 2, nt = bid & 3;
  long arow0 = (long)bm * 128;
  int ncol0 = nt * 128;
  int lane = tid & 63, wid = tid >> 6;
  int wm = (wid >> 1) * 64, wn = (wid & 1) * 64;
  int lr = lane & 15, kg = lane >> 4;
  int l7 = lr & 7;

  f32x4 acc[4][4];
#pragma unroll
  for (int i = 0; i < 4; ++i)
#pragma unroll
    for (int j = 0; j < 4; ++j) acc[i][j] = (f32x4)0.f;

  for (int k0 = 0; k0 < 512; k0 += 64) {
#pragma unroll
    for (int i = 0; i < 4; ++i) {
      int c = i * 256 + tid;
      int r = c >> 3;
      int col = ((c & 7) ^ (r & 7)) * 8;  // pre-swizzled source column
      load_lds16(A + (arow0 + r) * 512 + k0 + col, &sA[c * 8]);
      load_lds16(Wb + (long)(ncol0 + r) * 512 + k0 + col, &sB[c * 8]);
    }
    __syncthreads();
#pragma unroll
    for (int kf = 0; kf < 2; ++kf) {
      int u = (kf * 4 + kg) ^ l7;  // swizzled read unit
      bf16x8 av[4], bv[4];
#pragma unroll
      for (int i = 0; i < 4; ++i) {
        av[i] = *(const bf16x8*)&sA[(wm + i * 16 + lr) * 64 + u * 8];
        bv[i] = *(const bf16x8*)&sB[(wn + i * 16 + lr) * 64 + u * 8];
      }
#pragma unroll
      for (int mi = 0; mi < 4; ++mi)
#pragma unroll
        for (int ni = 0; ni < 4; ++ni)
          acc[mi][ni] = __builtin_amdgcn_mfma_f32_16x16x32_bf16(
              av[mi], bv[ni], acc[mi][ni], 0, 0, 0);
    }
    __syncthreads();
  }
  int mg = kg * 4;
#pragma unroll
  for (int mi = 0; mi < 4; ++mi) {
#pragma unroll
    for (int ni = 0; ni < 4; ++ni) {
      int ncol = ncol0 + wn + ni * 16 + lr;
      float bv = b2[ncol];
#pragma unroll
      for (int rgi = 0; rgi < 4; ++rgi) {
        long row = arow0 + wm + mi * 16 + mg + rgi;  // tau
        float val = acc[mi][ni][rgi] + bv;
        const float* src = (row < 16384) ? rc + row * 512 : utt + (row - 16384) * 512;
        val += src[ncol];
        float* dst = (row < 16384) ? out + 33554432 + row * 512
                                   : out + (row - 16384) * 512;
        dst[ncol] = val;
      }
    }
  }
}

// ---------------- new_state ----------------
__global__ __launch_bounds__(256, 4) void k_state(const u16* __restrict__ X,
                                                  float* __restrict__ out) {
  int i = blockIdx.x * 256 + threadIdx.x;
  if (i >= 491520) return;
  int j = i % 30;
  int rest = i / 30;
  int d = rest & 511;
  int b = rest >> 9;
  out[41943040 + i] = bf2f(X[((long)(2530 + j) * Bb + b) * 512 + d]);
}

extern "C" void kernel_launch(void* const* d_in, const int* in_sizes, int n_in,
                              void* d_out, int out_size, void* d_ws, size_t ws_size,
                              hipStream_t stream) {
  const float* utt = (const float*)d_in[0];
  const float* rc = (const float*)d_in[1];
  const float* state = (const float*)d_in[2];
  const float* ln1g = (const float*)d_in[3];
  const float* ln1b = (const float*)d_in[4];
  const float* w1 = (const float*)d_in[5];
  const float* b1 = (const float*)d_in[6];
  const float* cw = (const float*)d_in[7];
  const float* cb = (const float*)d_in[8];
  const float* ln2g = (const float*)d_in[9];
  const float* ln2b = (const float*)d_in[10];
  const float* w2 = (const float*)d_in[11];
  const float* b2 = (const float*)d_in[12];
  float* out = (float*)d_out;

  char* ws = (char*)d_ws;
  u16* w1b = (u16*)ws;                                         // 1 MB
  u16* w2b = (u16*)(ws + (1 << 20));                           // 512 KB
  float* cwT = (float*)(ws + (1 << 20) + (1 << 19));           // 64 KB
  u16* lnx = (u16*)(ws + (1 << 20) + (1 << 19) + (1 << 16));   // 80 MiB (ln_x, later z)
  u16* xbuf = lnx + (size_t)MROWS * Dm;                        // 80 MiB

  k_cast<<<512, 256, 0, stream>>>(w1, w1b, 1024 * 512);
  k_cast<<<256, 256, 0, stream>>>(w2, w2b, 512 * 512);
  k_wt<<<62, 256, 0, stream>>>(cw, cwT);
  k_ln1<<<MROWS / 4, 256, 0, stream>>>(utt, rc, ln1g, ln1b, lnx);
  k_gemm1<<<2560, 256, 0, stream>>>(lnx, w1b, b1, xbuf);
  k_conv_ln2<<<dim3(160, 32), 512, 0, stream>>>(xbuf, state, cwT, cb, ln2g, ln2b, lnx);
  k_gemm2<<<2560, 256, 0, stream>>>(lnx, w2b, b2, utt, rc, out);
  k_state<<<1920, 256, 0, stream>>>(xbuf, out);
}